// Round 1
// baseline (419.682 us; speedup 1.0000x reference)
//
#include <hip/hip_runtime.h>
#include <hip/hip_bf16.h>

typedef __bf16 bf16x8 __attribute__((ext_vector_type(8)));
typedef float  f32x4  __attribute__((ext_vector_type(4)));
typedef short  short8 __attribute__((ext_vector_type(8)));
typedef float  f32x4v __attribute__((ext_vector_type(4)));

#define B_SZ 4
#define N_SZ 16384
#define DIM_SZ 384
#define H_SZ 8
#define C_SZ 48
#define M_SZ 24

static constexpr float SCALE = 0.37991784282579627f;   // 48^-0.25
static constexpr float RSM   = 0.20412414523193154f;   // 1/sqrt(24)
static constexpr float EPS_V = 1e-6f;

// ---------------- async global->LDS (16B per lane) ----------------
__device__ __forceinline__ void gld_lds16(void* lds, const void* g) {
  __builtin_amdgcn_global_load_lds(
      (const __attribute__((address_space(1))) unsigned int*)g,
      (__attribute__((address_space(3))) unsigned int*)lds, 16, 0, 0);
}

__device__ __forceinline__ float bf2f(short s) {
  union { unsigned u; float f; } cv;
  cv.u = ((unsigned)(unsigned short)s) << 16;
  return cv.f;
}

// ---------------- bf16 GEMM, C = A[M][K] @ B^T[N][K] ----------------
// tile 128x128, BK=64, 256 threads = 4 waves (2x2), each wave 64x64 = 4x4 frags.
// EPI 0: bf16 output. EPI 1: fp32 output + bias.
template<int EPI>
__global__ __launch_bounds__(256) void gemm_bt(
    const __bf16* __restrict__ A, const __bf16* __restrict__ Bm,
    void* __restrict__ Cout, const float* __restrict__ bias,
    int M, int N, int K) {
  __shared__ __align__(16) __bf16 As[128][64];
  __shared__ __align__(16) __bf16 Bs[128][64];
  const int t    = threadIdx.x;
  const int lane = t & 63;
  const int wid  = t >> 6;
  const int wr   = wid >> 1, wc = wid & 1;
  const int row0 = blockIdx.y * 128, col0 = blockIdx.x * 128;
  const int lr   = lane & 15;          // frag row (A) / col (B)
  const int kg   = (lane >> 4) << 3;   // k offset within 32
  const int to   = t * 16;             // staging byte base
  f32x4 acc[4][4] = {};

  for (int kt = 0; kt < K; kt += 64) {
    __syncthreads();
    #pragma unroll
    for (int i = 0; i < 4; ++i) {
      const int o  = i * 4096 + to;    // linear LDS byte offset
      const int r  = o >> 7;           // 128 B per row (64 bf16)
      const int ce = (o & 127) >> 1;   // element within row
      gld_lds16((char*)(&As[0][0]) + o, A  + (size_t)(row0 + r) * K + kt + ce);
      gld_lds16((char*)(&Bs[0][0]) + o, Bm + (size_t)(col0 + r) * K + kt + ce);
    }
    __syncthreads();   // compiler emits s_waitcnt vmcnt(0) before barrier

    #pragma unroll
    for (int kk = 0; kk < 64; kk += 32) {
      bf16x8 af[4], bfr[4];
      #pragma unroll
      for (int mi = 0; mi < 4; ++mi)
        af[mi] = *(const bf16x8*)(&As[wr*64 + mi*16 + lr][kk + kg]);
      #pragma unroll
      for (int ni = 0; ni < 4; ++ni)
        bfr[ni] = *(const bf16x8*)(&Bs[wc*64 + ni*16 + lr][kk + kg]);
      #pragma unroll
      for (int mi = 0; mi < 4; ++mi)
        #pragma unroll
        for (int ni = 0; ni < 4; ++ni)
          acc[mi][ni] = __builtin_amdgcn_mfma_f32_16x16x32_bf16(
              af[mi], bfr[ni], acc[mi][ni], 0, 0, 0);
    }
  }

  // C/D layout: col = lane&15, row = (lane>>4)*4 + j   [verified m89/m91]
  const int cr = (lane >> 4) << 2;
  #pragma unroll
  for (int mi = 0; mi < 4; ++mi) {
    #pragma unroll
    for (int ni = 0; ni < 4; ++ni) {
      const int col = col0 + wc*64 + ni*16 + lr;
      #pragma unroll
      for (int j = 0; j < 4; ++j) {
        const int row = row0 + wr*64 + mi*16 + cr + j;
        const float v = acc[mi][ni][j];
        if (EPI == 1) {
          ((float*)Cout)[(size_t)row * N + col] = v + bias[col];
        } else {
          ((__bf16*)Cout)[(size_t)row * N + col] = (__bf16)v;
        }
      }
    }
  }
}

// ---------------- feature map: phi[24] from one 48-wide row ----------------
__device__ __forceinline__ void compute_phi(const __bf16* __restrict__ row,
                                            const float* __restrict__ w_lds,
                                            float* __restrict__ phi) {
  short8 raw[6];
  #pragma unroll
  for (int i = 0; i < 6; ++i)
    raw[i] = *(const short8*)(row + i * 8);
  float tv[48];
  float ss = 0.f;
  #pragma unroll
  for (int i = 0; i < 6; ++i) {
    #pragma unroll
    for (int j = 0; j < 8; ++j) {
      const float f = bf2f(raw[i][j]) * SCALE;
      tv[i*8 + j] = f;
      ss += f * f;
    }
  }
  const float hs = 0.5f * ss;
  #pragma unroll
  for (int m = 0; m < 24; ++m) {
    float d = -hs;
    #pragma unroll
    for (int c = 0; c < 48; ++c)
      d += tv[c] * w_lds[m*48 + c];
    phi[m] = __expf(d) * RSM;
  }
}

// ---------------- ktv + ksum: recompute phi_k, outer-product accumulate ----
// grid (32 chunks, H, B), 256 threads. Each chunk = 512 tokens, batches of 256.
// ownership: threads t<144: m = t/6 (24), c0 = (t%6)*8 (6 groups of 8 cols).
__global__ __launch_bounds__(256) void ktv_kernel(
    const __bf16* __restrict__ qkv, const float* __restrict__ w,
    float* __restrict__ ktv, float* __restrict__ ksum) {
  const int b = blockIdx.z, h = blockIdx.y, chunk = blockIdx.x;
  __shared__ float w_lds[1152];
  __shared__ float phi_lds[256][25];            // +1 pad: conflict-free writes
  __shared__ __align__(16) __bf16 v_lds[256][56]; // 112B rows: 8-way max on write
  const int t = threadIdx.x;
  for (int i = t; i < 1152; i += 256) w_lds[i] = w[h*1152 + i];
  const bool act = (t < 144);
  const int m  = t / 6;
  const int c0 = (t % 6) * 8;
  float acc[8] = {0,0,0,0,0,0,0,0};
  float ks = 0.f;
  const int n0 = chunk * 512;
  __syncthreads();

  for (int nb = 0; nb < 512; nb += 256) {
    const int n = n0 + nb + t;
    const __bf16* krow = qkv + (size_t)(b*N_SZ + n) * 1152 + DIM_SZ + h*C_SZ;
    // stage this token's v row
    #pragma unroll
    for (int i = 0; i < 6; ++i)
      *(short8*)(&v_lds[t][i*8]) = *(const short8*)(krow + DIM_SZ + i*8);
    float phi[24];
    compute_phi(krow, w_lds, phi);
    #pragma unroll
    for (int mm = 0; mm < 24; ++mm) phi_lds[t][mm] = phi[mm];
    __syncthreads();

    if (act) {
      for (int n2 = 0; n2 < 256; ++n2) {
        const float p = phi_lds[n2][m];
        if (c0 == 0) ks += p;
        const short8 v8 = *(const short8*)(&v_lds[n2][c0]);
        #pragma unroll
        for (int j = 0; j < 8; ++j)
          acc[j] += p * bf2f(v8[j]);
      }
    }
    __syncthreads();
  }

  if (act) {
    float* kp = ktv + ((size_t)(b*H_SZ + h) * 24 + m) * 48 + c0;
    #pragma unroll
    for (int j = 0; j < 8; ++j) atomicAdd(kp + j, acc[j]);
    if (c0 == 0) atomicAdd(ksum + (b*H_SZ + h)*24 + m, ks);
  }
}

// ---------------- out_attn: recompute phi_q, D, phi_q @ ktv / D ----------
__global__ __launch_bounds__(256) void attn_out_kernel(
    const __bf16* __restrict__ qkv, const float* __restrict__ w,
    const float* __restrict__ ktv, const float* __restrict__ ksum,
    __bf16* __restrict__ attn) {
  const int b = blockIdx.z, h = blockIdx.y, blk = blockIdx.x;
  __shared__ float w_lds[1152];
  __shared__ float ktv_lds[1152];
  __shared__ float ks_lds[24];
  const int t = threadIdx.x;
  for (int i = t; i < 1152; i += 256) {
    w_lds[i]   = w[h*1152 + i];
    ktv_lds[i] = ktv[(size_t)(b*H_SZ + h)*1152 + i];
  }
  if (t < 24) ks_lds[t] = ksum[(b*H_SZ + h)*24 + t];
  __syncthreads();

  const int n = blk * 256 + t;
  const __bf16* qrow = qkv + (size_t)(b*N_SZ + n) * 1152 + h*C_SZ;
  float phi[24];
  compute_phi(qrow, w_lds, phi);

  float D = EPS_V;
  #pragma unroll
  for (int mm = 0; mm < 24; ++mm) D += phi[mm] * ks_lds[mm];
  const float inv = 1.0f / D;

  float o[48] = {};
  #pragma unroll
  for (int mm = 0; mm < 24; ++mm) {
    const float p = phi[mm];
    #pragma unroll
    for (int c = 0; c < 48; ++c)
      o[c] += p * ktv_lds[mm*48 + c];
  }

  __bf16* orow = attn + (size_t)(b*N_SZ + n) * DIM_SZ + h*C_SZ;
  #pragma unroll
  for (int i = 0; i < 6; ++i) {
    short8 pk;
    #pragma unroll
    for (int j = 0; j < 8; ++j) {
      const __bf16 bv = (__bf16)(o[i*8 + j] * inv);
      pk[j] = __builtin_bit_cast(short, bv);
    }
    *(short8*)(orow + i*8) = pk;
  }
}

// ---------------- fp32 -> bf16 convert, 8 elems/thread ----------------
__global__ __launch_bounds__(256) void f32_to_bf16_kernel(
    const float* __restrict__ in, __bf16* __restrict__ out, int n8) {
  const int i = blockIdx.x * blockDim.x + threadIdx.x;
  if (i >= n8) return;
  const f32x4v a = *(const f32x4v*)(in + (size_t)i*8);
  const f32x4v c = *(const f32x4v*)(in + (size_t)i*8 + 4);
  short8 pk;
  #pragma unroll
  for (int j = 0; j < 4; ++j) {
    pk[j]     = __builtin_bit_cast(short, (__bf16)a[j]);
    pk[4 + j] = __builtin_bit_cast(short, (__bf16)c[j]);
  }
  *(short8*)(out + (size_t)i*8) = pk;
}

extern "C" void kernel_launch(void* const* d_in, const int* in_sizes, int n_in,
                              void* d_out, int out_size, void* d_ws, size_t ws_size,
                              hipStream_t stream) {
  (void)in_sizes; (void)n_in; (void)out_size; (void)ws_size;
  const float* x      = (const float*)d_in[0];
  const float* qkv_w  = (const float*)d_in[1];
  const float* proj_w = (const float*)d_in[2];
  const float* proj_b = (const float*)d_in[3];
  const float* w      = (const float*)d_in[4];
  float* out = (float*)d_out;

  const size_t BN_TOT = (size_t)B_SZ * N_SZ;           // 65536
  char* ws = (char*)d_ws;
  size_t off = 0;
  auto alloc = [&](size_t bytes) {
    char* p = ws + off;
    off += (bytes + 255) & ~(size_t)255;
    return p;
  };
  __bf16* x_bf  = (__bf16*)alloc(BN_TOT * DIM_SZ * 2);       // 50.3 MB (reused as attn)
  __bf16* qw_bf = (__bf16*)alloc((size_t)3 * DIM_SZ * DIM_SZ * 2);
  __bf16* pw_bf = (__bf16*)alloc((size_t)DIM_SZ * DIM_SZ * 2);
  __bf16* qkv   = (__bf16*)alloc(BN_TOT * 3 * DIM_SZ * 2);   // 151 MB
  float*  ktv   = (float*)alloc((size_t)B_SZ * H_SZ * M_SZ * C_SZ * 4);
  float*  ksum  = (float*)alloc((size_t)B_SZ * H_SZ * M_SZ * 4);
  __bf16* attn  = x_bf;  // alias: x_bf dead after GEMM1

  hipMemsetAsync(ktv,  0, (size_t)B_SZ * H_SZ * M_SZ * C_SZ * 4, stream);
  hipMemsetAsync(ksum, 0, (size_t)B_SZ * H_SZ * M_SZ * 4, stream);

  // conversions
  {
    const int n8x = (int)(BN_TOT * DIM_SZ / 8);
    f32_to_bf16_kernel<<<(n8x + 255)/256, 256, 0, stream>>>(x, x_bf, n8x);
    const int n8q = 3 * DIM_SZ * DIM_SZ / 8;
    f32_to_bf16_kernel<<<(n8q + 255)/256, 256, 0, stream>>>(qkv_w, qw_bf, n8q);
    const int n8p = DIM_SZ * DIM_SZ / 8;
    f32_to_bf16_kernel<<<(n8p + 255)/256, 256, 0, stream>>>(proj_w, pw_bf, n8p);
  }

  // qkv = x @ qkv_w.T   (65536 x 1152 x 384)
  gemm_bt<0><<<dim3(3*DIM_SZ/128, BN_TOT/128), 256, 0, stream>>>(
      x_bf, qw_bf, qkv, nullptr, (int)BN_TOT, 3*DIM_SZ, DIM_SZ);

  // ktv / ksum
  ktv_kernel<<<dim3(32, H_SZ, B_SZ), 256, 0, stream>>>(qkv, w, ktv, ksum);

  // attn = (phi_q @ ktv) / D
  attn_out_kernel<<<dim3(N_SZ/256, H_SZ, B_SZ), 256, 0, stream>>>(
      qkv, w, ktv, ksum, attn);

  // out = attn @ proj_w.T + proj_b   (65536 x 384 x 384)
  gemm_bt<1><<<dim3(DIM_SZ/128, BN_TOT/128), 256, 0, stream>>>(
      attn, pw_bf, out, proj_b, (int)BN_TOT, DIM_SZ, DIM_SZ);
}

// Round 2
// 303.121 us; speedup vs baseline: 1.3845x; 1.3845x over previous
//
#include <hip/hip_runtime.h>
#include <hip/hip_bf16.h>

typedef __bf16 bf16x8 __attribute__((ext_vector_type(8)));
typedef float  f32x4  __attribute__((ext_vector_type(4)));
typedef short  short8 __attribute__((ext_vector_type(8)));
typedef short  short4v __attribute__((ext_vector_type(4)));
typedef float  f32x4v __attribute__((ext_vector_type(4)));

#define B_SZ 4
#define N_SZ 16384
#define DIM_SZ 384
#define H_SZ 8
#define C_SZ 48
#define M_SZ 24

static constexpr float SCALE = 0.37991784282579627f;   // 48^-0.25
static constexpr float RSM   = 0.20412414523193154f;   // 1/sqrt(24)
static constexpr float EPS_V = 1e-6f;

// ---------------- async global->LDS (16B per lane) ----------------
__device__ __forceinline__ void gld_lds16(void* lds, const void* g) {
  __builtin_amdgcn_global_load_lds(
      (const __attribute__((address_space(1))) unsigned int*)g,
      (__attribute__((address_space(3))) unsigned int*)lds, 16, 0, 0);
}

__device__ __forceinline__ float bf2f(short s) {
  union { unsigned u; float f; } cv;
  cv.u = ((unsigned)(unsigned short)s) << 16;
  return cv.f;
}
__device__ __forceinline__ short f2bf_s(float f) {
  const __bf16 b = (__bf16)f;
  return __builtin_bit_cast(short, b);
}

// ---------------- bf16 GEMM, C = A[M][K] @ B^T[N][K] ----------------
template<int EPI>
__global__ __launch_bounds__(256) void gemm_bt(
    const __bf16* __restrict__ A, const __bf16* __restrict__ Bm,
    void* __restrict__ Cout, const float* __restrict__ bias,
    int M, int N, int K) {
  __shared__ __align__(16) __bf16 As[128][64];
  __shared__ __align__(16) __bf16 Bs[128][64];
  const int t    = threadIdx.x;
  const int lane = t & 63;
  const int wid  = t >> 6;
  const int wr   = wid >> 1, wc = wid & 1;
  const int row0 = blockIdx.y * 128, col0 = blockIdx.x * 128;
  const int lr   = lane & 15;
  const int kg   = (lane >> 4) << 3;
  const int to   = t * 16;
  f32x4 acc[4][4] = {};

  for (int kt = 0; kt < K; kt += 64) {
    __syncthreads();
    #pragma unroll
    for (int i = 0; i < 4; ++i) {
      const int o  = i * 4096 + to;
      const int r  = o >> 7;
      const int ce = (o & 127) >> 1;
      gld_lds16((char*)(&As[0][0]) + o, A  + (size_t)(row0 + r) * K + kt + ce);
      gld_lds16((char*)(&Bs[0][0]) + o, Bm + (size_t)(col0 + r) * K + kt + ce);
    }
    __syncthreads();

    #pragma unroll
    for (int kk = 0; kk < 64; kk += 32) {
      bf16x8 af[4], bfr[4];
      #pragma unroll
      for (int mi = 0; mi < 4; ++mi)
        af[mi] = *(const bf16x8*)(&As[wr*64 + mi*16 + lr][kk + kg]);
      #pragma unroll
      for (int ni = 0; ni < 4; ++ni)
        bfr[ni] = *(const bf16x8*)(&Bs[wc*64 + ni*16 + lr][kk + kg]);
      #pragma unroll
      for (int mi = 0; mi < 4; ++mi)
        #pragma unroll
        for (int ni = 0; ni < 4; ++ni)
          acc[mi][ni] = __builtin_amdgcn_mfma_f32_16x16x32_bf16(
              af[mi], bfr[ni], acc[mi][ni], 0, 0, 0);
    }
  }

  const int cr = (lane >> 4) << 2;
  #pragma unroll
  for (int mi = 0; mi < 4; ++mi) {
    #pragma unroll
    for (int ni = 0; ni < 4; ++ni) {
      const int col = col0 + wc*64 + ni*16 + lr;
      #pragma unroll
      for (int j = 0; j < 4; ++j) {
        const int row = row0 + wr*64 + mi*16 + cr + j;
        const float v = acc[mi][ni][j];
        if (EPI == 1) {
          ((float*)Cout)[(size_t)row * N + col] = v + bias[col];
        } else {
          ((__bf16*)Cout)[(size_t)row * N + col] = (__bf16)v;
        }
      }
    }
  }
}

// ---------------- w prep: w_bf[h][hi/lo][32][64] = scale*w, hi/lo split ----
__global__ __launch_bounds__(256) void wprep_kernel(
    const float* __restrict__ w, __bf16* __restrict__ w_bf) {
  const int idx = blockIdx.x * 256 + threadIdx.x;   // 8*32*64 = 16384
  if (idx >= 8*32*64) return;
  const int c = idx & 63, m = (idx >> 6) & 31, h = idx >> 11;
  const float v = (m < 24 && c < 48) ? w[(h*24 + m)*48 + c] * SCALE : 0.f;
  const __bf16 hi = (__bf16)v;
  const float lo = v - (float)hi;
  w_bf[((size_t)(h*2 + 0)*32 + m)*64 + c] = hi;
  w_bf[((size_t)(h*2 + 1)*32 + m)*64 + c] = (__bf16)lo;
}

// ---------------- phi kernel: MFMA logits, writes phi_q[n][32], phi_kT[24][N], ksum
// grid (N/64, B), 512 threads = 8 waves = 8 heads; each wave: 64 tokens.
__global__ __launch_bounds__(512) void phi_kernel(
    const __bf16* __restrict__ qkv, const __bf16* __restrict__ w_bf,
    __bf16* __restrict__ phi_q, __bf16* __restrict__ phi_kT,
    float* __restrict__ ksum) {
  const int b    = blockIdx.y;
  const int tok0 = blockIdx.x * 64;
  const int t    = threadIdx.x;
  const int wv   = t >> 6;            // head
  const int lane = t & 63;
  const int l15  = lane & 15;
  const int g    = lane >> 4;
  const int h    = wv;
  const int bh   = b * H_SZ + h;
  __shared__ float hs_lds[2][512];

  #pragma unroll
  for (int src = 0; src < 2; ++src) {
    // ---- self-dot (lane <-> token tok0+lane) ----
    {
      const __bf16* row = qkv + ((size_t)(b*N_SZ) + tok0 + lane)*1152
                              + src*DIM_SZ + h*C_SZ;
      float ss = 0.f;
      #pragma unroll
      for (int i = 0; i < 6; ++i) {
        const short8 r = *(const short8*)(row + i*8);
        #pragma unroll
        for (int j = 0; j < 8; ++j) {
          const float f = bf2f(r[j]) * SCALE;
          ss += f * f;
        }
      }
      hs_lds[src][wv*64 + lane] = 0.5f * ss;
    }

    // ---- MFMA logits: acc[tt][mt], K=48 (2 ksteps, tail zero-padded via w) --
    f32x4 acc[4][2] = {};
    #pragma unroll
    for (int ks = 0; ks < 2; ++ks) {
      bf16x8 af[4];
      #pragma unroll
      for (int tt = 0; tt < 4; ++tt)
        af[tt] = *(const bf16x8*)(qkv + ((size_t)(b*N_SZ) + tok0 + tt*16 + l15)*1152
                                      + src*DIM_SZ + h*C_SZ + ks*32 + g*8);
      #pragma unroll
      for (int v = 0; v < 2; ++v) {     // hi / lo of w
        const bf16x8 b0 = *(const bf16x8*)(w_bf + ((size_t)(h*2+v)*32 + l15)*64 + ks*32 + g*8);
        const bf16x8 b1 = *(const bf16x8*)(w_bf + ((size_t)(h*2+v)*32 + 16 + l15)*64 + ks*32 + g*8);
        #pragma unroll
        for (int tt = 0; tt < 4; ++tt) {
          acc[tt][0] = __builtin_amdgcn_mfma_f32_16x16x32_bf16(af[tt], b0, acc[tt][0], 0,0,0);
          acc[tt][1] = __builtin_amdgcn_mfma_f32_16x16x32_bf16(af[tt], b1, acc[tt][1], 0,0,0);
        }
      }
    }

    // ---- exp + writes.  C layout: col(m)=l15, row(token)=g*4+jj ----
    float kss[2] = {0.f, 0.f};
    #pragma unroll
    for (int tt = 0; tt < 4; ++tt) {
      #pragma unroll
      for (int mt = 0; mt < 2; ++mt) {
        const int m = mt*16 + l15;
        float ph[4];
        #pragma unroll
        for (int jj = 0; jj < 4; ++jj) {
          const int trow = tt*16 + g*4 + jj;
          const float hs = hs_lds[src][wv*64 + trow];
          ph[jj] = (m < 24) ? __expf(acc[tt][mt][jj] - hs) * RSM : 0.f;
        }
        if (src == 0) {
          #pragma unroll
          for (int jj = 0; jj < 4; ++jj)
            phi_q[((size_t)bh*N_SZ + tok0 + tt*16 + g*4 + jj)*32 + m] = (__bf16)ph[jj];
        } else if (m < 24) {
          short4v pk;
          #pragma unroll
          for (int jj = 0; jj < 4; ++jj) pk[jj] = f2bf_s(ph[jj]);
          *(short4v*)(phi_kT + ((size_t)bh*24 + m)*N_SZ + tok0 + tt*16 + g*4) = pk;
          kss[mt] += ph[0] + ph[1] + ph[2] + ph[3];
        }
      }
    }
    if (src == 1) {
      #pragma unroll
      for (int mt = 0; mt < 2; ++mt) {
        float v = kss[mt];
        v += __shfl_xor(v, 16);
        v += __shfl_xor(v, 32);
        if (g == 0 && (mt == 0 || l15 < 8))
          atomicAdd(&ksum[bh*24 + mt*16 + l15], v);
      }
    }
  }
}

// ---------------- ktv: MFMA  ktv[m][c] = sum_n phi_kT[m][n] * v[n][c] -----
// grid (8 splits, H, B), 256 thr / 4 waves; wave owns private vT slab.
__global__ __launch_bounds__(256) void ktv_kernel(
    const __bf16* __restrict__ qkv, const __bf16* __restrict__ phi_kT,
    float* __restrict__ ktv_f) {
  const int b = blockIdx.z, h = blockIdx.y, sp = blockIdx.x;
  const int t = threadIdx.x, wv = t >> 6, lane = t & 63;
  const int l15 = lane & 15, g = lane >> 4;
  const int bh = b*H_SZ + h;
  __shared__ __align__(16) __bf16 vT[4][48][40];   // [wave][c][n] pad 40
  __shared__ float red[4][24*48];
  f32x4 acc[2][3] = {};
  const int nbase = sp*2048 + wv*512;

  for (int step = 0; step < 16; ++step) {
    const int n0 = nbase + step*32;
    // stage v transposed: 192 tasks (32 tok x 6 pieces), 3 per lane
    #pragma unroll
    for (int it = 0; it < 3; ++it) {
      const int task = it*64 + lane;
      const int tk = task / 6, p = task % 6;
      const short8 r = *(const short8*)(qkv + ((size_t)(b*N_SZ) + n0 + tk)*1152
                                            + 2*DIM_SZ + h*C_SZ + p*8);
      #pragma unroll
      for (int e = 0; e < 8; ++e)
        vT[wv][p*8 + e][tk] = __builtin_bit_cast(__bf16, (short)r[e]);
    }
    // A-frags from phi_kT (global, contiguous 16B)
    bf16x8 a0 = *(const bf16x8*)(phi_kT + ((size_t)bh*24 + l15)*N_SZ + n0 + g*8);
    bf16x8 a1;
    if (l15 < 8)
      a1 = *(const bf16x8*)(phi_kT + ((size_t)bh*24 + 16 + l15)*N_SZ + n0 + g*8);
    else
      a1 = bf16x8{};
    #pragma unroll
    for (int ct = 0; ct < 3; ++ct) {
      const bf16x8 bf = *(const bf16x8*)(&vT[wv][ct*16 + l15][g*8]);
      acc[0][ct] = __builtin_amdgcn_mfma_f32_16x16x32_bf16(a0, bf, acc[0][ct], 0,0,0);
      acc[1][ct] = __builtin_amdgcn_mfma_f32_16x16x32_bf16(a1, bf, acc[1][ct], 0,0,0);
    }
  }

  // reduce: C layout col(c)=l15, row(m)=g*4+jj
  #pragma unroll
  for (int mt = 0; mt < 2; ++mt)
    #pragma unroll
    for (int ct = 0; ct < 3; ++ct)
      #pragma unroll
      for (int jj = 0; jj < 4; ++jj) {
        const int row = mt*16 + g*4 + jj;
        if (row < 24)
          red[wv][row*48 + ct*16 + l15] = acc[mt][ct][jj];
      }
  __syncthreads();
  for (int i = t; i < 1152; i += 256) {
    const float s = red[0][i] + red[1][i] + red[2][i] + red[3][i];
    atomicAdd(&ktv_f[bh*1152 + i], s);
  }
}

// ---------------- reduce: ktv_f32 -> ktvT bf16 [48][32] (m padded) --------
__global__ __launch_bounds__(256) void reduce_kernel(
    const float* __restrict__ ktv_f, __bf16* __restrict__ ktvT) {
  const int bh = blockIdx.x;
  for (int i = threadIdx.x; i < 48*32; i += 256) {
    const int c = i >> 5, m = i & 31;
    const float v = (m < 24) ? ktv_f[bh*1152 + m*48 + c] : 0.f;
    ktvT[(size_t)bh*1536 + i] = (__bf16)v;
  }
}

// ---------------- pv: out[n][c] = (phi_q[n] @ ktv) / D ------------------
// grid (N/256, H, B), 256 thr / 4 waves; wave: 64 tokens.
__global__ __launch_bounds__(256) void pv_kernel(
    const __bf16* __restrict__ phi_q, const __bf16* __restrict__ ktvT,
    const float* __restrict__ ksum, __bf16* __restrict__ attn) {
  const int b = blockIdx.z, h = blockIdx.y, blk = blockIdx.x;
  const int t = threadIdx.x, wv = t >> 6, lane = t & 63;
  const int l15 = lane & 15, g = lane >> 4;
  const int bh = b*H_SZ + h;
  __shared__ __align__(16) __bf16 kt[48][40];
  __shared__ float ksl[24];
  __shared__ float invD[256];

  if (t < 192) {
    const int row = t >> 2, ch = t & 3;
    *(bf16x8*)(&kt[row][ch*8]) =
        *(const bf16x8*)(ktvT + (size_t)bh*1536 + row*32 + ch*8);
  }
  if (t < 24) ksl[t] = ksum[bh*24 + t];
  __syncthreads();

  // D pass: thread t <-> token blk*256+t
  {
    const __bf16* prow = phi_q + ((size_t)bh*N_SZ + blk*256 + t)*32;
    const short8 p0 = *(const short8*)(prow);
    const short8 p1 = *(const short8*)(prow + 8);
    const short8 p2 = *(const short8*)(prow + 16);
    float d = 0.f;
    #pragma unroll
    for (int j = 0; j < 8; ++j) {
      d += bf2f(p0[j]) * ksl[j];
      d += bf2f(p1[j]) * ksl[8 + j];
      d += bf2f(p2[j]) * ksl[16 + j];
    }
    invD[t] = 1.0f / (d + EPS_V);
  }
  __syncthreads();

  // PV MFMA
  f32x4 acc[4][3] = {};
  #pragma unroll
  for (int tt = 0; tt < 4; ++tt) {
    const bf16x8 af = *(const bf16x8*)(phi_q +
        ((size_t)bh*N_SZ + blk*256 + wv*64 + tt*16 + l15)*32 + g*8);
    #pragma unroll
    for (int ct = 0; ct < 3; ++ct) {
      const bf16x8 bf = *(const bf16x8*)(&kt[ct*16 + l15][g*8]);
      acc[tt][ct] = __builtin_amdgcn_mfma_f32_16x16x32_bf16(af, bf, acc[tt][ct], 0,0,0);
    }
  }

  // epilogue: col(c)=l15, row(token)=g*4+jj
  #pragma unroll
  for (int tt = 0; tt < 4; ++tt)
    #pragma unroll
    for (int ct = 0; ct < 3; ++ct)
      #pragma unroll
      for (int jj = 0; jj < 4; ++jj) {
        const int lrow = wv*64 + tt*16 + g*4 + jj;
        const float v = acc[tt][ct][jj] * invD[lrow];
        attn[((size_t)(b*N_SZ) + blk*256 + lrow)*DIM_SZ + h*C_SZ + ct*16 + l15]
            = (__bf16)v;
      }
}

// ---------------- fp32 -> bf16 convert ----------------
__global__ __launch_bounds__(256) void f32_to_bf16_kernel(
    const float* __restrict__ in, __bf16* __restrict__ out, int n8) {
  const int i = blockIdx.x * blockDim.x + threadIdx.x;
  if (i >= n8) return;
  const f32x4v a = *(const f32x4v*)(in + (size_t)i*8);
  const f32x4v c = *(const f32x4v*)(in + (size_t)i*8 + 4);
  short8 pk;
  #pragma unroll
  for (int j = 0; j < 4; ++j) {
    pk[j]     = f2bf_s(a[j]);
    pk[4 + j] = f2bf_s(c[j]);
  }
  *(short8*)(out + (size_t)i*8) = pk;
}

extern "C" void kernel_launch(void* const* d_in, const int* in_sizes, int n_in,
                              void* d_out, int out_size, void* d_ws, size_t ws_size,
                              hipStream_t stream) {
  (void)in_sizes; (void)n_in; (void)out_size; (void)ws_size;
  const float* x      = (const float*)d_in[0];
  const float* qkv_w  = (const float*)d_in[1];
  const float* proj_w = (const float*)d_in[2];
  const float* proj_b = (const float*)d_in[3];
  const float* w      = (const float*)d_in[4];
  float* out = (float*)d_out;

  const size_t BN_TOT = (size_t)B_SZ * N_SZ;           // 65536
  char* ws = (char*)d_ws;
  size_t off = 0;
  auto alloc = [&](size_t bytes) {
    char* p = ws + off;
    off += (bytes + 255) & ~(size_t)255;
    return p;
  };
  __bf16* x_bf   = (__bf16*)alloc(BN_TOT * DIM_SZ * 2);        // 50.3 MB
  __bf16* qw_bf  = (__bf16*)alloc((size_t)3 * DIM_SZ * DIM_SZ * 2);
  __bf16* pw_bf  = (__bf16*)alloc((size_t)DIM_SZ * DIM_SZ * 2);
  __bf16* qkv    = (__bf16*)alloc(BN_TOT * 3 * DIM_SZ * 2);    // 151 MB
  __bf16* phi_kT = (__bf16*)alloc((size_t)B_SZ * H_SZ * 24 * N_SZ * 2); // 25.2 MB
  float*  ktv_f  = (float*)alloc((size_t)32 * 1152 * 4);
  float*  ksum   = (float*)alloc((size_t)32 * 24 * 4);
  __bf16* ktvT   = (__bf16*)alloc((size_t)32 * 1536 * 2);
  __bf16* w_bf   = (__bf16*)alloc((size_t)8 * 2 * 32 * 64 * 2);
  __bf16* phi_q  = x_bf;   // alias: x dead after GEMM1 (33.5 MB <= 50.3 MB)
  __bf16* attn   = qkv;    // alias: qkv dead after ktv_kernel (50.3 <= 151 MB)

  hipMemsetAsync(ktv_f, 0, (size_t)32 * 1152 * 4, stream);
  hipMemsetAsync(ksum,  0, (size_t)32 * 24 * 4, stream);

  // conversions + w prep
  {
    const int n8x = (int)(BN_TOT * DIM_SZ / 8);
    f32_to_bf16_kernel<<<(n8x + 255)/256, 256, 0, stream>>>(x, x_bf, n8x);
    const int n8q = 3 * DIM_SZ * DIM_SZ / 8;
    f32_to_bf16_kernel<<<(n8q + 255)/256, 256, 0, stream>>>(qkv_w, qw_bf, n8q);
    const int n8p = DIM_SZ * DIM_SZ / 8;
    f32_to_bf16_kernel<<<(n8p + 255)/256, 256, 0, stream>>>(proj_w, pw_bf, n8p);
    wprep_kernel<<<64, 256, 0, stream>>>(w, w_bf);
  }

  // qkv = x @ qkv_w.T   (65536 x 1152 x 384)
  gemm_bt<0><<<dim3(3*DIM_SZ/128, BN_TOT/128), 256, 0, stream>>>(
      x_bf, qw_bf, qkv, nullptr, (int)BN_TOT, 3*DIM_SZ, DIM_SZ);

  // phi (q + kT + ksum)
  phi_kernel<<<dim3(N_SZ/64, B_SZ), 512, 0, stream>>>(
      qkv, w_bf, phi_q, phi_kT, ksum);

  // ktv (split-K atomics) + pack to bf16 transposed
  ktv_kernel<<<dim3(8, H_SZ, B_SZ), 256, 0, stream>>>(qkv, phi_kT, ktv_f);
  reduce_kernel<<<32, 256, 0, stream>>>(ktv_f, ktvT);

  // attn = (phi_q @ ktv) / D
  pv_kernel<<<dim3(N_SZ/256, H_SZ, B_SZ), 256, 0, stream>>>(
      phi_q, ktvT, ksum, attn);

  // out = attn @ proj_w.T + proj_b   (65536 x 384 x 384)
  gemm_bt<1><<<dim3(DIM_SZ/128, BN_TOT/128), 256, 0, stream>>>(
      attn, pw_bf, out, proj_b, (int)BN_TOT, DIM_SZ, DIM_SZ);
}

// Round 3
// 272.780 us; speedup vs baseline: 1.5385x; 1.1112x over previous
//
#include <hip/hip_runtime.h>
#include <hip/hip_bf16.h>

typedef __bf16 bf16x8 __attribute__((ext_vector_type(8)));
typedef float  f32x4  __attribute__((ext_vector_type(4)));
typedef short  short8 __attribute__((ext_vector_type(8)));
typedef float  f32x4v __attribute__((ext_vector_type(4)));

#define B_SZ 4
#define N_SZ 16384
#define DIM_SZ 384
#define H_SZ 8
#define C_SZ 48
#define M_SZ 24

static constexpr float SCALE = 0.37991784282579627f;   // 48^-0.25
static constexpr float RSM   = 0.20412414523193154f;   // 1/sqrt(24)
static constexpr float EPS_V = 1e-6f;

// kvll column map: [k: 0..383 | v: 384..767 | logit_q: 768..959 | logit_k: 960..1151]

// ---------------- async global->LDS (16B per lane) ----------------
__device__ __forceinline__ void gld_lds16(void* lds, const void* g) {
  __builtin_amdgcn_global_load_lds(
      (const __attribute__((address_space(1))) unsigned int*)g,
      (__attribute__((address_space(3))) unsigned int*)lds, 16, 0, 0);
}

__device__ __forceinline__ float bf2f(short s) {
  union { unsigned u; float f; } cv;
  cv.u = ((unsigned)(unsigned short)s) << 16;
  return cv.f;
}
__device__ __forceinline__ short f2bf_s(float f) {
  const __bf16 b = (__bf16)f;
  return __builtin_bit_cast(short, b);
}

// ---------------- bf16 GEMM, C = A[M][K] @ B^T[N][K], XCD-swizzled --------
template<int EPI>
__global__ __launch_bounds__(256) void gemm_bt(
    const __bf16* __restrict__ A, const __bf16* __restrict__ Bm,
    void* __restrict__ Cout, const float* __restrict__ bias,
    int M, int N, int K) {
  __shared__ __align__(16) __bf16 As[128][64];
  __shared__ __align__(16) __bf16 Bs[128][64];
  const int t    = threadIdx.x;
  const int lane = t & 63;
  const int wid  = t >> 6;
  const int wr   = wid >> 1, wc = wid & 1;
  // bijective XCD chunk swizzle (m204 form): each XCD owns contiguous
  // row-panel chunks -> A-panel L2 locality; B is L2-resident per XCD.
  const int gx   = gridDim.x;
  const int nwg  = gx * gridDim.y;
  const int orig = blockIdx.y * gx + blockIdx.x;
  const int qq   = nwg >> 3, rr = nwg & 7;
  const int xcd  = orig & 7, pos = orig >> 3;
  const int id   = (xcd < rr ? xcd*(qq+1) : rr*(qq+1) + (xcd-rr)*qq) + pos;
  const int row0 = (id / gx) * 128, col0 = (id % gx) * 128;
  const int lr   = lane & 15;
  const int kg   = (lane >> 4) << 3;
  const int to   = t * 16;
  f32x4 acc[4][4] = {};

  for (int kt = 0; kt < K; kt += 64) {
    __syncthreads();
    #pragma unroll
    for (int i = 0; i < 4; ++i) {
      const int o  = i * 4096 + to;
      const int r  = o >> 7;
      const int ce = (o & 127) >> 1;
      gld_lds16((char*)(&As[0][0]) + o, A  + (size_t)(row0 + r) * K + kt + ce);
      gld_lds16((char*)(&Bs[0][0]) + o, Bm + (size_t)(col0 + r) * K + kt + ce);
    }
    __syncthreads();

    #pragma unroll
    for (int kk = 0; kk < 64; kk += 32) {
      bf16x8 af[4], bfr[4];
      #pragma unroll
      for (int mi = 0; mi < 4; ++mi)
        af[mi] = *(const bf16x8*)(&As[wr*64 + mi*16 + lr][kk + kg]);
      #pragma unroll
      for (int ni = 0; ni < 4; ++ni)
        bfr[ni] = *(const bf16x8*)(&Bs[wc*64 + ni*16 + lr][kk + kg]);
      #pragma unroll
      for (int mi = 0; mi < 4; ++mi)
        #pragma unroll
        for (int ni = 0; ni < 4; ++ni)
          acc[mi][ni] = __builtin_amdgcn_mfma_f32_16x16x32_bf16(
              af[mi], bfr[ni], acc[mi][ni], 0, 0, 0);
    }
  }

  const int cr = (lane >> 4) << 2;
  #pragma unroll
  for (int mi = 0; mi < 4; ++mi) {
    #pragma unroll
    for (int ni = 0; ni < 4; ++ni) {
      const int col = col0 + wc*64 + ni*16 + lr;
      #pragma unroll
      for (int j = 0; j < 4; ++j) {
        const int row = row0 + wr*64 + mi*16 + cr + j;
        const float v = acc[mi][ni][j];
        if (EPI == 1) {
          ((float*)Cout)[(size_t)row * N + col] = v + bias[col];
        } else {
          ((__bf16*)Cout)[(size_t)row * N + col] = (__bf16)v;
        }
      }
    }
  }
}

// ---- combined log-weights: Baug rows 768..1151 = scale * (w @ qkv_w_side) --
__global__ __launch_bounds__(256) void wlog_kernel(
    const float* __restrict__ qkv_w, const float* __restrict__ w,
    __bf16* __restrict__ Baug) {
  const int idx = blockIdx.x * 256 + threadIdx.x;   // 2*192*384
  if (idx >= 2*192*384) return;
  const int d = idx % 384, rs = idx / 384;
  const int side = rs / 192, hm = rs % 192;
  const int h = hm / 24;
  const float* wr = w + (size_t)hm * 48;
  const float* qw = qkv_w + ((size_t)(side*384 + h*48)) * 384 + d;
  float acc = 0.f;
  #pragma unroll
  for (int c = 0; c < 48; ++c)
    acc += wr[c] * qw[(size_t)c * 384];
  Baug[(size_t)(768 + side*192 + hm) * 384 + d] = (__bf16)(acc * SCALE);
}

// ---------------- ktv fused: phi_k from [k|lk], MFMA ktv + ksum ----------
// grid (32 splits, H, B), 256 thr / 4 waves; per wave 128 tokens = 4 steps.
__global__ __launch_bounds__(256) void ktv_fused(
    const __bf16* __restrict__ kvll, float* __restrict__ ktv_f,
    float* __restrict__ ksum) {
  const int b = blockIdx.z, h = blockIdx.y, sp = blockIdx.x;
  const int t = threadIdx.x, wv = t >> 6, lane = t & 63;
  const int l15 = lane & 15, g = lane >> 4;
  const int bh = b*H_SZ + h;
  __shared__ __align__(16) __bf16 vT[4][48][40];    // [wave][c][tok]
  __shared__ __align__(16) __bf16 phiT[4][24][40];  // [wave][m][tok]
  __shared__ float red[4][1152];
  f32x4 acc[2][3] = {};
  f32x4 aks[2] = {};                 // ksum via ones-column MFMA
  const int nbase = sp*512 + wv*128;

  bf16x8 ones{};                     // B-frag: col 0 = all-ones
  if (l15 == 0)
    #pragma unroll
    for (int j = 0; j < 8; ++j) ones[j] = (__bf16)1.0f;

  for (int step = 0; step < 4; ++step) {
    const int n0 = nbase + step*32;
    // stage v transposed: 192 tasks (32 tok x 6 pieces), 3 per lane
    #pragma unroll
    for (int it = 0; it < 3; ++it) {
      const int task = it*64 + lane;
      const int tk = task / 6, p = task % 6;
      const short8 r = *(const short8*)(kvll + ((size_t)(b*N_SZ) + n0 + tk)*1152
                                            + 384 + h*C_SZ + p*8);
      #pragma unroll
      for (int e = 0; e < 8; ++e)
        vT[wv][p*8 + e][tk] = __builtin_bit_cast(__bf16, (short)r[e]);
    }
    // phi_k for 32 tokens (lanes < 32): hs from k, logits precomputed
    if (lane < 32) {
      const __bf16* row = kvll + ((size_t)(b*N_SZ) + n0 + lane)*1152 + h*C_SZ;
      float ss = 0.f;
      #pragma unroll
      for (int i = 0; i < 6; ++i) {
        const short8 r = *(const short8*)(row + i*8);
        #pragma unroll
        for (int j = 0; j < 8; ++j) { const float f = bf2f(r[j]) * SCALE; ss += f*f; }
      }
      const float hs = 0.5f * ss;
      const __bf16* lk = kvll + ((size_t)(b*N_SZ) + n0 + lane)*1152 + 960 + h*24;
      #pragma unroll
      for (int i = 0; i < 3; ++i) {
        const short8 r = *(const short8*)(lk + i*8);
        #pragma unroll
        for (int j = 0; j < 8; ++j)
          phiT[wv][i*8 + j][lane] = (__bf16)(__expf(bf2f(r[j]) - hs) * RSM);
      }
    }
    // MFMA: ktv[m][c] += phi[m][tok] * vT[c][tok]
    const bf16x8 a0 = *(const bf16x8*)(&phiT[wv][l15][g*8]);
    bf16x8 a1{};
    if (l15 < 8) a1 = *(const bf16x8*)(&phiT[wv][16 + l15][g*8]);
    #pragma unroll
    for (int ct = 0; ct < 3; ++ct) {
      const bf16x8 bfr = *(const bf16x8*)(&vT[wv][ct*16 + l15][g*8]);
      acc[0][ct] = __builtin_amdgcn_mfma_f32_16x16x32_bf16(a0, bfr, acc[0][ct], 0,0,0);
      acc[1][ct] = __builtin_amdgcn_mfma_f32_16x16x32_bf16(a1, bfr, acc[1][ct], 0,0,0);
    }
    aks[0] = __builtin_amdgcn_mfma_f32_16x16x32_bf16(a0, ones, aks[0], 0,0,0);
    aks[1] = __builtin_amdgcn_mfma_f32_16x16x32_bf16(a1, ones, aks[1], 0,0,0);
  }

  // ksum: C col(l15)=0 holds sums; row m = g*4+jj
  if (l15 == 0) {
    #pragma unroll
    for (int mt = 0; mt < 2; ++mt)
      #pragma unroll
      for (int jj = 0; jj < 4; ++jj) {
        const int m = mt*16 + g*4 + jj;
        if (m < 24) atomicAdd(&ksum[bh*24 + m], aks[mt][jj]);
      }
  }
  // ktv: col(c)=l15, row(m)=g*4+jj
  #pragma unroll
  for (int mt = 0; mt < 2; ++mt)
    #pragma unroll
    for (int ct = 0; ct < 3; ++ct)
      #pragma unroll
      for (int jj = 0; jj < 4; ++jj) {
        const int row = mt*16 + g*4 + jj;
        if (row < 24)
          red[wv][row*48 + ct*16 + l15] = acc[mt][ct][jj];
      }
  __syncthreads();
  for (int i = t; i < 1152; i += 256) {
    const float s = red[0][i] + red[1][i] + red[2][i] + red[3][i];
    atomicAdd(&ktv_f[bh*1152 + i], s);
  }
}

// ---------------- reduce: ktv_f32 -> ktvT bf16 [48][32] (m padded) --------
__global__ __launch_bounds__(256) void reduce_kernel(
    const float* __restrict__ ktv_f, __bf16* __restrict__ ktvT) {
  const int bh = blockIdx.x;
  for (int i = threadIdx.x; i < 48*32; i += 256) {
    const int c = i >> 5, m = i & 31;
    const float v = (m < 24) ? ktv_f[bh*1152 + m*48 + c] : 0.f;
    ktvT[(size_t)bh*1536 + i] = (__bf16)v;
  }
}

// ---------------- pv fused: phi_q = exp(lq)*RSM in-reg (hs cancels) -------
// grid (N/256, H, B), 256 thr / 4 waves; wave: 64 tokens.
__global__ __launch_bounds__(256) void pv_fused(
    const __bf16* __restrict__ kvll, const __bf16* __restrict__ ktvT,
    const float* __restrict__ ksum, __bf16* __restrict__ attn) {
  const int b = blockIdx.z, h = blockIdx.y, blk = blockIdx.x;
  const int t = threadIdx.x, wv = t >> 6, lane = t & 63;
  const int l15 = lane & 15, g = lane >> 4;
  const int bh = b*H_SZ + h;
  __shared__ __align__(16) __bf16 kt[48][40];
  __shared__ float ksl[24];
  __shared__ float invD[256];

  if (t < 192) {
    const int row = t >> 2, ch = t & 3;
    *(bf16x8*)(&kt[row][ch*8]) =
        *(const bf16x8*)(ktvT + (size_t)bh*1536 + row*32 + ch*8);
  }
  if (t < 24) ksl[t] = ksum[bh*24 + t];
  __syncthreads();

  // D pass: thread t <-> token blk*256+t (same bf16 rounding as MFMA frags)
  {
    const size_t tok = (size_t)(b*N_SZ) + blk*256 + t;
    const __bf16* lq = kvll + tok*1152 + 768 + h*24;
    float d = EPS_V;
    #pragma unroll
    for (int i = 0; i < 3; ++i) {
      const short8 r = *(const short8*)(lq + i*8);
      #pragma unroll
      for (int j = 0; j < 8; ++j)
        d += bf2f(f2bf_s(__expf(bf2f(r[j])) * RSM)) * ksl[i*8 + j];
    }
    invD[t] = 1.0f / d;
  }
  __syncthreads();

  // PV MFMA
  f32x4 acc[4][3] = {};
  #pragma unroll
  for (int tt = 0; tt < 4; ++tt) {
    bf16x8 af{};
    if (g < 3) {
      const size_t tok = (size_t)(b*N_SZ) + blk*256 + wv*64 + tt*16 + l15;
      const short8 r = *(const short8*)(kvll + tok*1152 + 768 + h*24 + g*8);
      #pragma unroll
      for (int j = 0; j < 8; ++j)
        af[j] = (__bf16)(__expf(bf2f(r[j])) * RSM);
    }
    #pragma unroll
    for (int ct = 0; ct < 3; ++ct) {
      const bf16x8 bfr = *(const bf16x8*)(&kt[ct*16 + l15][g*8]);
      acc[tt][ct] = __builtin_amdgcn_mfma_f32_16x16x32_bf16(af, bfr, acc[tt][ct], 0,0,0);
    }
  }

  // epilogue: col(c)=l15, row(token)=g*4+jj
  #pragma unroll
  for (int tt = 0; tt < 4; ++tt)
    #pragma unroll
    for (int ct = 0; ct < 3; ++ct)
      #pragma unroll
      for (int jj = 0; jj < 4; ++jj) {
        const int lrow = wv*64 + tt*16 + g*4 + jj;
        const float v = acc[tt][ct][jj] * invD[lrow];
        attn[((size_t)(b*N_SZ) + blk*256 + lrow)*DIM_SZ + h*C_SZ + ct*16 + l15]
            = (__bf16)v;
      }
}

// ---------------- fp32 -> bf16 convert ----------------
__global__ __launch_bounds__(256) void f32_to_bf16_kernel(
    const float* __restrict__ in, __bf16* __restrict__ out, int n8) {
  const int i = blockIdx.x * blockDim.x + threadIdx.x;
  if (i >= n8) return;
  const f32x4v a = *(const f32x4v*)(in + (size_t)i*8);
  const f32x4v c = *(const f32x4v*)(in + (size_t)i*8 + 4);
  short8 pk;
  #pragma unroll
  for (int j = 0; j < 4; ++j) {
    pk[j]     = f2bf_s(a[j]);
    pk[4 + j] = f2bf_s(c[j]);
  }
  *(short8*)(out + (size_t)i*8) = pk;
}

extern "C" void kernel_launch(void* const* d_in, const int* in_sizes, int n_in,
                              void* d_out, int out_size, void* d_ws, size_t ws_size,
                              hipStream_t stream) {
  (void)in_sizes; (void)n_in; (void)out_size; (void)ws_size;
  const float* x      = (const float*)d_in[0];
  const float* qkv_w  = (const float*)d_in[1];
  const float* proj_w = (const float*)d_in[2];
  const float* proj_b = (const float*)d_in[3];
  const float* w      = (const float*)d_in[4];
  float* out = (float*)d_out;

  const size_t BN_TOT = (size_t)B_SZ * N_SZ;           // 65536
  char* ws = (char*)d_ws;
  size_t off = 0;
  auto alloc = [&](size_t bytes) {
    char* p = ws + off;
    off += (bytes + 255) & ~(size_t)255;
    return p;
  };
  __bf16* x_bf  = (__bf16*)alloc(BN_TOT * DIM_SZ * 2);          // 50.3 MB
  __bf16* Baug  = (__bf16*)alloc((size_t)1152 * 384 * 2);       // 0.88 MB
  __bf16* pw_bf = (__bf16*)alloc((size_t)DIM_SZ * DIM_SZ * 2);
  __bf16* kvll  = (__bf16*)alloc(BN_TOT * 1152 * 2);            // 151 MB
  float*  ktv_f = (float*)alloc((size_t)32 * 1152 * 4);
  float*  ksum  = (float*)alloc((size_t)32 * 24 * 4);
  __bf16* ktvT  = (__bf16*)alloc((size_t)32 * 1536 * 2);
  __bf16* attn  = x_bf;   // alias: x_bf dead after GEMM1

  hipMemsetAsync(ktv_f, 0, (size_t)32 * 1152 * 4, stream);
  hipMemsetAsync(ksum,  0, (size_t)32 * 24 * 4, stream);

  // conversions + combined weights
  {
    const int n8x = (int)(BN_TOT * DIM_SZ / 8);
    f32_to_bf16_kernel<<<(n8x + 255)/256, 256, 0, stream>>>(x, x_bf, n8x);
    // Baug rows 0..767 = k,v weight rows of qkv_w (rows 384..1151)
    const int n8kv = 768 * 384 / 8;
    f32_to_bf16_kernel<<<(n8kv + 255)/256, 256, 0, stream>>>(
        qkv_w + (size_t)384 * 384, Baug, n8kv);
    const int n8p = DIM_SZ * DIM_SZ / 8;
    f32_to_bf16_kernel<<<(n8p + 255)/256, 256, 0, stream>>>(proj_w, pw_bf, n8p);
    // Baug rows 768..1151 = scale * (w @ qkv_w_{q,k})
    wlog_kernel<<<(2*192*384 + 255)/256, 256, 0, stream>>>(qkv_w, w, Baug);
  }

  // kvll = x @ Baug.T : [k | v | logit_q | logit_k]   (65536 x 1152 x 384)
  gemm_bt<0><<<dim3(1152/128, BN_TOT/128), 256, 0, stream>>>(
      x_bf, Baug, kvll, nullptr, (int)BN_TOT, 1152, DIM_SZ);

  // ktv + ksum (phi_k fused)
  ktv_fused<<<dim3(32, H_SZ, B_SZ), 256, 0, stream>>>(kvll, ktv_f, ksum);
  reduce_kernel<<<32, 256, 0, stream>>>(ktv_f, ktvT);

  // attn = (phi_q @ ktv) / D   (phi_q from logit_q, hs_q cancels)
  pv_fused<<<dim3(N_SZ/256, H_SZ, B_SZ), 256, 0, stream>>>(
      kvll, ktvT, ksum, attn);

  // out = attn @ proj_w.T + proj_b   (65536 x 384 x 384)
  gemm_bt<1><<<dim3(DIM_SZ/128, BN_TOT/128), 256, 0, stream>>>(
      attn, pw_bf, out, proj_b, (int)BN_TOT, DIM_SZ, DIM_SZ);
}

// Round 4
// 247.042 us; speedup vs baseline: 1.6988x; 1.1042x over previous
//
#include <hip/hip_runtime.h>
#include <hip/hip_bf16.h>

typedef __bf16 bf16x8 __attribute__((ext_vector_type(8)));
typedef float  f32x4  __attribute__((ext_vector_type(4)));
typedef short  short8 __attribute__((ext_vector_type(8)));
typedef float  f32x4v __attribute__((ext_vector_type(4)));

#define B_SZ 4
#define N_SZ 16384
#define DIM_SZ 384
#define H_SZ 8
#define C_SZ 48
#define M_SZ 24

static constexpr float SCALE = 0.37991784282579627f;   // 48^-0.25
static constexpr float RSM   = 0.20412414523193154f;   // 1/sqrt(24)
static constexpr float EPS_V = 1e-6f;

// kvll column map: [k: 0..383 | v: 384..767 | logit_q: 768..959 | logit_k: 960..1151]

// ---------------- async global->LDS (16B per lane) ----------------
__device__ __forceinline__ void gld_lds16(void* lds, const void* g) {
  __builtin_amdgcn_global_load_lds(
      (const __attribute__((address_space(1))) unsigned int*)g,
      (__attribute__((address_space(3))) unsigned int*)lds, 16, 0, 0);
}

__device__ __forceinline__ float bf2f(short s) {
  union { unsigned u; float f; } cv;
  cv.u = ((unsigned)(unsigned short)s) << 16;
  return cv.f;
}
__device__ __forceinline__ short f2bf_s(float f) {
  const __bf16 b = (__bf16)f;
  return __builtin_bit_cast(short, b);
}

// ============ deep-pipelined bf16 GEMM, C = A[M][K] @ B^T[N][K] ============
// BM=256 BN=128 BK=64, 512 thr = 8 waves (4M x 2N), per-wave 64x64 (4x4 frags).
// 3 LDS K-tile buffers (48KB each: A 32KB + B 16KB), counted vmcnt(6),
// raw s_barrier (no vmcnt(0) drain), XOR-swizzled LDS (slot ^= row&7) with
// pre-swizzled global source (linear global_load_lds dest).
template<int EPI>
__global__ __launch_bounds__(512, 2) void gemm8(
    const __bf16* __restrict__ A, const __bf16* __restrict__ Bm,
    void* __restrict__ Cout, const float* __restrict__ bias,
    int M, int N, int K) {
  extern __shared__ __align__(16) char lds[];   // 3 * 49152
  const int t    = threadIdx.x;
  const int lane = t & 63;
  const int wid  = t >> 6;
  const int wm   = wid >> 1;          // 0..3  (m-direction)
  const int wn   = wid & 1;           // 0..1  (n-direction)
  const int l15  = lane & 15;
  const int kgq  = lane >> 4;         // 0..3

  // bijective XCD chunk swizzle (m204)
  const int gx   = gridDim.x;
  const int nwg  = gx * gridDim.y;
  const int orig = blockIdx.y * gx + blockIdx.x;
  const int qq   = nwg >> 3, rr = nwg & 7;
  const int xcd  = orig & 7, pos = orig >> 3;
  const int id   = (xcd < rr ? xcd*(qq+1) : rr*(qq+1) + (xcd-rr)*qq) + pos;
  const int row0 = (id / gx) * 256, col0 = (id % gx) * 128;

  const int nt = K >> 6;              // K-tiles

  // staging map: thread t -> row sr (of each 64-row stripe), slot ss.
  // LDS gets (row, s) <- global (row, s ^ (row&7));  row&7 == sr&7.
  const int sr  = t >> 3;
  const int sgA = (t & 7) ^ (sr & 7);

  auto stage = [&](int kt) {
    char* buf = lds + (kt % 3) * 49152;
    const size_t kofs = (size_t)kt * 64 + sgA * 8;
    #pragma unroll
    for (int ai = 0; ai < 4; ++ai)
      gld_lds16(buf + ai*8192 + t*16,
                A + (size_t)(row0 + ai*64 + sr) * K + kofs);
    #pragma unroll
    for (int bi = 0; bi < 2; ++bi)
      gld_lds16(buf + 32768 + bi*8192 + t*16,
                Bm + (size_t)(col0 + bi*64 + sr) * K + kofs);
  };

  f32x4 acc[4][4] = {};

  // prologue: 2 stage-sets in flight
  stage(0);
  if (nt > 1) stage(1);

  for (int kt = 0; kt < nt; ++kt) {
    // entry: wait own stage(kt) loads (all threads do this before barrier),
    // leave stage(kt+1)'s 6 loads in flight.
    if (kt < nt - 1) asm volatile("s_waitcnt vmcnt(6)" ::: "memory");
    else             asm volatile("s_waitcnt vmcnt(0)" ::: "memory");
    __builtin_amdgcn_s_barrier();
    __builtin_amdgcn_sched_barrier(0);

    char* buf = lds + (kt % 3) * 49152;
    if (kt + 2 < nt) stage(kt + 2);   // buffer (kt+2)%3: last read in block kt-1

    // B fragments once per K-tile (held in regs across the 4 m-phases)
    bf16x8 bfr[4][2];
    #pragma unroll
    for (int ni = 0; ni < 4; ++ni) {
      const int brow = wn*64 + ni*16 + l15;
      #pragma unroll
      for (int kk = 0; kk < 2; ++kk)
        bfr[ni][kk] = *(const bf16x8*)(buf + 32768 + brow*128
                          + ((kk*64 + kgq*16) ^ ((brow & 7) << 4)));
    }
    #pragma unroll
    for (int mi = 0; mi < 4; ++mi) {
      const int arow = wm*64 + mi*16 + l15;
      const bf16x8 a0 = *(const bf16x8*)(buf + arow*128
                          + ((kgq*16)      ^ ((arow & 7) << 4)));
      const bf16x8 a1 = *(const bf16x8*)(buf + arow*128
                          + ((64 + kgq*16) ^ ((arow & 7) << 4)));
      __builtin_amdgcn_s_setprio(1);
      #pragma unroll
      for (int ni = 0; ni < 4; ++ni) {
        acc[mi][ni] = __builtin_amdgcn_mfma_f32_16x16x32_bf16(a0, bfr[ni][0], acc[mi][ni], 0,0,0);
        acc[mi][ni] = __builtin_amdgcn_mfma_f32_16x16x32_bf16(a1, bfr[ni][1], acc[mi][ni], 0,0,0);
      }
      __builtin_amdgcn_s_setprio(0);
    }
  }

  // epilogue: C/D layout col = l15, row = (lane>>4)*4 + j
  const int cr = (lane >> 4) << 2;
  #pragma unroll
  for (int mi = 0; mi < 4; ++mi) {
    #pragma unroll
    for (int ni = 0; ni < 4; ++ni) {
      const int col = col0 + wn*64 + ni*16 + l15;
      #pragma unroll
      for (int j = 0; j < 4; ++j) {
        const int row = row0 + wm*64 + mi*16 + cr + j;
        const float v = acc[mi][ni][j];
        if (EPI == 1) {
          ((float*)Cout)[(size_t)row * N + col] = v + bias[col];
        } else {
          ((__bf16*)Cout)[(size_t)row * N + col] = (__bf16)v;
        }
      }
    }
  }
}

// ---- combined log-weights: Baug rows 768..1151 = scale * (w @ qkv_w_side) --
__global__ __launch_bounds__(256) void wlog_kernel(
    const float* __restrict__ qkv_w, const float* __restrict__ w,
    __bf16* __restrict__ Baug) {
  const int idx = blockIdx.x * 256 + threadIdx.x;   // 2*192*384
  if (idx >= 2*192*384) return;
  const int d = idx % 384, rs = idx / 384;
  const int side = rs / 192, hm = rs % 192;
  const int h = hm / 24;
  const float* wr = w + (size_t)hm * 48;
  const float* qw = qkv_w + ((size_t)(side*384 + h*48)) * 384 + d;
  float acc = 0.f;
  #pragma unroll
  for (int c = 0; c < 48; ++c)
    acc += wr[c] * qw[(size_t)c * 384];
  Baug[(size_t)(768 + side*192 + hm) * 384 + d] = (__bf16)(acc * SCALE);
}

// ---------------- ktv fused: phi_k from [k|lk], MFMA ktv + ksum ----------
__global__ __launch_bounds__(256) void ktv_fused(
    const __bf16* __restrict__ kvll, float* __restrict__ ktv_f,
    float* __restrict__ ksum) {
  const int b = blockIdx.z, h = blockIdx.y, sp = blockIdx.x;
  const int t = threadIdx.x, wv = t >> 6, lane = t & 63;
  const int l15 = lane & 15, g = lane >> 4;
  const int bh = b*H_SZ + h;
  __shared__ __align__(16) __bf16 vT[4][48][40];    // [wave][c][tok]
  __shared__ __align__(16) __bf16 phiT[4][24][40];  // [wave][m][tok]
  __shared__ float red[4][1152];
  f32x4 acc[2][3] = {};
  f32x4 aks[2] = {};                 // ksum via ones-column MFMA
  const int nbase = sp*512 + wv*128;

  bf16x8 ones{};                     // B-frag: col 0 = all-ones
  if (l15 == 0)
    #pragma unroll
    for (int j = 0; j < 8; ++j) ones[j] = (__bf16)1.0f;

  for (int step = 0; step < 4; ++step) {
    const int n0 = nbase + step*32;
    #pragma unroll
    for (int it = 0; it < 3; ++it) {
      const int task = it*64 + lane;
      const int tk = task / 6, p = task % 6;
      const short8 r = *(const short8*)(kvll + ((size_t)(b*N_SZ) + n0 + tk)*1152
                                            + 384 + h*C_SZ + p*8);
      #pragma unroll
      for (int e = 0; e < 8; ++e)
        vT[wv][p*8 + e][tk] = __builtin_bit_cast(__bf16, (short)r[e]);
    }
    if (lane < 32) {
      const __bf16* row = kvll + ((size_t)(b*N_SZ) + n0 + lane)*1152 + h*C_SZ;
      float ss = 0.f;
      #pragma unroll
      for (int i = 0; i < 6; ++i) {
        const short8 r = *(const short8*)(row + i*8);
        #pragma unroll
        for (int j = 0; j < 8; ++j) { const float f = bf2f(r[j]) * SCALE; ss += f*f; }
      }
      const float hs = 0.5f * ss;
      const __bf16* lk = kvll + ((size_t)(b*N_SZ) + n0 + lane)*1152 + 960 + h*24;
      #pragma unroll
      for (int i = 0; i < 3; ++i) {
        const short8 r = *(const short8*)(lk + i*8);
        #pragma unroll
        for (int j = 0; j < 8; ++j)
          phiT[wv][i*8 + j][lane] = (__bf16)(__expf(bf2f(r[j]) - hs) * RSM);
      }
    }
    const bf16x8 a0 = *(const bf16x8*)(&phiT[wv][l15][g*8]);
    bf16x8 a1{};
    if (l15 < 8) a1 = *(const bf16x8*)(&phiT[wv][16 + l15][g*8]);
    #pragma unroll
    for (int ct = 0; ct < 3; ++ct) {
      const bf16x8 bfr = *(const bf16x8*)(&vT[wv][ct*16 + l15][g*8]);
      acc[0][ct] = __builtin_amdgcn_mfma_f32_16x16x32_bf16(a0, bfr, acc[0][ct], 0,0,0);
      acc[1][ct] = __builtin_amdgcn_mfma_f32_16x16x32_bf16(a1, bfr, acc[1][ct], 0,0,0);
    }
    aks[0] = __builtin_amdgcn_mfma_f32_16x16x32_bf16(a0, ones, aks[0], 0,0,0);
    aks[1] = __builtin_amdgcn_mfma_f32_16x16x32_bf16(a1, ones, aks[1], 0,0,0);
  }

  if (l15 == 0) {
    #pragma unroll
    for (int mt = 0; mt < 2; ++mt)
      #pragma unroll
      for (int jj = 0; jj < 4; ++jj) {
        const int m = mt*16 + g*4 + jj;
        if (m < 24) atomicAdd(&ksum[bh*24 + m], aks[mt][jj]);
      }
  }
  #pragma unroll
  for (int mt = 0; mt < 2; ++mt)
    #pragma unroll
    for (int ct = 0; ct < 3; ++ct)
      #pragma unroll
      for (int jj = 0; jj < 4; ++jj) {
        const int row = mt*16 + g*4 + jj;
        if (row < 24)
          red[wv][row*48 + ct*16 + l15] = acc[mt][ct][jj];
      }
  __syncthreads();
  for (int i = t; i < 1152; i += 256) {
    const float s = red[0][i] + red[1][i] + red[2][i] + red[3][i];
    atomicAdd(&ktv_f[bh*1152 + i], s);
  }
}

// ---------------- reduce: ktv_f32 -> ktvT bf16 [48][32] (m padded) --------
__global__ __launch_bounds__(256) void reduce_kernel(
    const float* __restrict__ ktv_f, __bf16* __restrict__ ktvT) {
  const int bh = blockIdx.x;
  for (int i = threadIdx.x; i < 48*32; i += 256) {
    const int c = i >> 5, m = i & 31;
    const float v = (m < 24) ? ktv_f[bh*1152 + m*48 + c] : 0.f;
    ktvT[(size_t)bh*1536 + i] = (__bf16)v;
  }
}

// ---------------- pv fused: phi_q = exp(lq)*RSM in-reg (hs cancels) -------
__global__ __launch_bounds__(256) void pv_fused(
    const __bf16* __restrict__ kvll, const __bf16* __restrict__ ktvT,
    const float* __restrict__ ksum, __bf16* __restrict__ attn) {
  const int b = blockIdx.z, h = blockIdx.y, blk = blockIdx.x;
  const int t = threadIdx.x, wv = t >> 6, lane = t & 63;
  const int l15 = lane & 15, g = lane >> 4;
  const int bh = b*H_SZ + h;
  __shared__ __align__(16) __bf16 kt[48][40];
  __shared__ float ksl[24];
  __shared__ float invD[256];

  if (t < 192) {
    const int row = t >> 2, ch = t & 3;
    *(bf16x8*)(&kt[row][ch*8]) =
        *(const bf16x8*)(ktvT + (size_t)bh*1536 + row*32 + ch*8);
  }
  if (t < 24) ksl[t] = ksum[bh*24 + t];
  __syncthreads();

  {
    const size_t tok = (size_t)(b*N_SZ) + blk*256 + t;
    const __bf16* lq = kvll + tok*1152 + 768 + h*24;
    float d = EPS_V;
    #pragma unroll
    for (int i = 0; i < 3; ++i) {
      const short8 r = *(const short8*)(lq + i*8);
      #pragma unroll
      for (int j = 0; j < 8; ++j)
        d += bf2f(f2bf_s(__expf(bf2f(r[j])) * RSM)) * ksl[i*8 + j];
    }
    invD[t] = 1.0f / d;
  }
  __syncthreads();

  f32x4 acc[4][3] = {};
  #pragma unroll
  for (int tt = 0; tt < 4; ++tt) {
    bf16x8 af{};
    if (g < 3) {
      const size_t tok = (size_t)(b*N_SZ) + blk*256 + wv*64 + tt*16 + l15;
      const short8 r = *(const short8*)(kvll + tok*1152 + 768 + h*24 + g*8);
      #pragma unroll
      for (int j = 0; j < 8; ++j)
        af[j] = (__bf16)(__expf(bf2f(r[j])) * RSM);
    }
    #pragma unroll
    for (int ct = 0; ct < 3; ++ct) {
      const bf16x8 bfr = *(const bf16x8*)(&kt[ct*16 + l15][g*8]);
      acc[tt][ct] = __builtin_amdgcn_mfma_f32_16x16x32_bf16(af, bfr, acc[tt][ct], 0,0,0);
    }
  }

  #pragma unroll
  for (int tt = 0; tt < 4; ++tt)
    #pragma unroll
    for (int ct = 0; ct < 3; ++ct)
      #pragma unroll
      for (int jj = 0; jj < 4; ++jj) {
        const int lrow = wv*64 + tt*16 + g*4 + jj;
        const float v = acc[tt][ct][jj] * invD[lrow];
        attn[((size_t)(b*N_SZ) + blk*256 + lrow)*DIM_SZ + h*C_SZ + ct*16 + l15]
            = (__bf16)v;
      }
}

// ---------------- fp32 -> bf16 convert ----------------
__global__ __launch_bounds__(256) void f32_to_bf16_kernel(
    const float* __restrict__ in, __bf16* __restrict__ out, int n8) {
  const int i = blockIdx.x * blockDim.x + threadIdx.x;
  if (i >= n8) return;
  const f32x4v a = *(const f32x4v*)(in + (size_t)i*8);
  const f32x4v c = *(const f32x4v*)(in + (size_t)i*8 + 4);
  short8 pk;
  #pragma unroll
  for (int j = 0; j < 4; ++j) {
    pk[j]     = f2bf_s(a[j]);
    pk[4 + j] = f2bf_s(c[j]);
  }
  *(short8*)(out + (size_t)i*8) = pk;
}

extern "C" void kernel_launch(void* const* d_in, const int* in_sizes, int n_in,
                              void* d_out, int out_size, void* d_ws, size_t ws_size,
                              hipStream_t stream) {
  (void)in_sizes; (void)n_in; (void)out_size; (void)ws_size;
  const float* x      = (const float*)d_in[0];
  const float* qkv_w  = (const float*)d_in[1];
  const float* proj_w = (const float*)d_in[2];
  const float* proj_b = (const float*)d_in[3];
  const float* w      = (const float*)d_in[4];
  float* out = (float*)d_out;

  const size_t BN_TOT = (size_t)B_SZ * N_SZ;           // 65536
  char* ws = (char*)d_ws;
  size_t off = 0;
  auto alloc = [&](size_t bytes) {
    char* p = ws + off;
    off += (bytes + 255) & ~(size_t)255;
    return p;
  };
  __bf16* x_bf  = (__bf16*)alloc(BN_TOT * DIM_SZ * 2);          // 50.3 MB
  __bf16* Baug  = (__bf16*)alloc((size_t)1152 * 384 * 2);       // 0.88 MB
  __bf16* pw_bf = (__bf16*)alloc((size_t)DIM_SZ * DIM_SZ * 2);
  __bf16* kvll  = (__bf16*)alloc(BN_TOT * 1152 * 2);            // 151 MB
  float*  ktv_f = (float*)alloc((size_t)32 * 1152 * 4);
  float*  ksum  = (float*)alloc((size_t)32 * 24 * 4);
  __bf16* ktvT  = (__bf16*)alloc((size_t)32 * 1536 * 2);
  __bf16* attn  = x_bf;   // alias: x_bf dead after GEMM1

  hipMemsetAsync(ktv_f, 0, (size_t)32 * 1152 * 4, stream);
  hipMemsetAsync(ksum,  0, (size_t)32 * 24 * 4, stream);

  // opt-in to 144KB dynamic LDS for the pipelined GEMM
  static const int LDS_BYTES = 3 * 49152;
  hipFuncSetAttribute(reinterpret_cast<const void*>(&gemm8<0>),
                      hipFuncAttributeMaxDynamicSharedMemorySize, LDS_BYTES);
  hipFuncSetAttribute(reinterpret_cast<const void*>(&gemm8<1>),
                      hipFuncAttributeMaxDynamicSharedMemorySize, LDS_BYTES);

  // conversions + combined weights
  {
    const int n8x = (int)(BN_TOT * DIM_SZ / 8);
    f32_to_bf16_kernel<<<(n8x + 255)/256, 256, 0, stream>>>(x, x_bf, n8x);
    const int n8kv = 768 * 384 / 8;
    f32_to_bf16_kernel<<<(n8kv + 255)/256, 256, 0, stream>>>(
        qkv_w + (size_t)384 * 384, Baug, n8kv);
    const int n8p = DIM_SZ * DIM_SZ / 8;
    f32_to_bf16_kernel<<<(n8p + 255)/256, 256, 0, stream>>>(proj_w, pw_bf, n8p);
    wlog_kernel<<<(2*192*384 + 255)/256, 256, 0, stream>>>(qkv_w, w, Baug);
  }

  // kvll = x @ Baug.T : [k | v | logit_q | logit_k]   (65536 x 1152 x 384)
  gemm8<0><<<dim3(1152/128, BN_TOT/256), 512, LDS_BYTES, stream>>>(
      x_bf, Baug, kvll, nullptr, (int)BN_TOT, 1152, DIM_SZ);

  // ktv + ksum (phi_k fused)
  ktv_fused<<<dim3(32, H_SZ, B_SZ), 256, 0, stream>>>(kvll, ktv_f, ksum);
  reduce_kernel<<<32, 256, 0, stream>>>(ktv_f, ktvT);

  // attn = (phi_q @ ktv) / D   (phi_q from logit_q, hs_q cancels)
  pv_fused<<<dim3(N_SZ/256, H_SZ, B_SZ), 256, 0, stream>>>(
      kvll, ktvT, ksum, attn);

  // out = attn @ proj_w.T + proj_b   (65536 x 384 x 384)
  gemm8<1><<<dim3(DIM_SZ/128, BN_TOT/256), 512, LDS_BYTES, stream>>>(
      attn, pw_bf, out, proj_b, (int)BN_TOT, DIM_SZ, DIM_SZ);
}